// Round 2
// baseline (349.715 us; speedup 1.0000x reference)
//
#include <hip/hip_runtime.h>

// ---------------- problem constants ----------------
#define N_NODES 10000
#define IN_DIM  512
#define OUT_DIM 128
#define NE      262144
#define K_DIM   10000

// ---------------- GEMM2 (adj @ h) tiling ----------------
#define BM 32
#define BN 128
#define BK 64
#define SPLITS 4
#define KSTEPS_TOTAL 157      // ceil(10000/64)
#define STEPS_PER_SPLIT 40    // 40+40+40+37 = 157

typedef __attribute__((ext_vector_type(8))) __bf16 bf16x8;
typedef __attribute__((ext_vector_type(4))) float  f32x4;

__device__ inline ushort f2bf(float f) {
    uint u = __float_as_uint(f);
    return (ushort)((u + 0x7fffu + ((u >> 16) & 1u)) >> 16);
}
__device__ inline float bf2f(ushort s) {
    return __uint_as_float(((uint)s) << 16);
}

// ---------------- kernel 0: WT = W^T (bf16), v = W2 @ w3[:128] ----------------
__global__ void k_prep(const float* __restrict__ w, const float* __restrict__ w2,
                       const float* __restrict__ w3, ushort* __restrict__ WT,
                       float* __restrict__ v) {
    const int t = threadIdx.x;  // 256
    for (int i = 0; i < IN_DIM * OUT_DIM / 256; ++i) {
        int idx = i * 256 + t;
        int k = idx >> 7, n = idx & 127;
        WT[n * IN_DIM + k] = f2bf(w[idx]);
    }
    float s = 0.f;
    for (int j = 0; j < OUT_DIM; ++j) s += w2[t * OUT_DIM + j] * w3[j];
    v[t] = s;
}

// ---------------- kernel 1: hT[c][r] = (x @ W)[r][c] bf16, MFMA, no LDS ----------------
__global__ __launch_bounds__(128) void k_xw(const float* __restrict__ x,
                                            const ushort* __restrict__ WT,
                                            ushort* __restrict__ hT) {
    const int tid = threadIdx.x, wave = tid >> 6, lane = tid & 63;
    const int lr = lane & 15, lg = lane >> 4;
    const int arow = blockIdx.x * 32 + wave * 16 + lr;
    const bool aok = arow < N_NODES;
    const float* pA = x + (size_t)arow * IN_DIM;

    f32x4 acc[8];
#pragma unroll
    for (int nf = 0; nf < 8; ++nf) acc[nf] = (f32x4){0.f, 0.f, 0.f, 0.f};

#pragma unroll 2
    for (int st = 0; st < 8; ++st) {
        const int k0 = st * 64;
        bf16x8 abf[2];
#pragma unroll
        for (int kh = 0; kh < 2; ++kh) {
            float4 a0 = make_float4(0.f, 0.f, 0.f, 0.f), a1 = a0;
            if (aok) {
                a0 = *(const float4*)(pA + k0 + kh * 32 + lg * 8);
                a1 = *(const float4*)(pA + k0 + kh * 32 + lg * 8 + 4);
            }
            ushort* ap = (ushort*)&abf[kh];
            ap[0] = f2bf(a0.x); ap[1] = f2bf(a0.y); ap[2] = f2bf(a0.z); ap[3] = f2bf(a0.w);
            ap[4] = f2bf(a1.x); ap[5] = f2bf(a1.y); ap[6] = f2bf(a1.z); ap[7] = f2bf(a1.w);
        }
#pragma unroll
        for (int kh = 0; kh < 2; ++kh)
#pragma unroll
            for (int nf = 0; nf < 8; ++nf) {
                bf16x8 bfv = *(const bf16x8*)(WT + (size_t)(nf * 16 + lr) * IN_DIM + k0 + kh * 32 + lg * 8);
                acc[nf] = __builtin_amdgcn_mfma_f32_16x16x32_bf16(abf[kh], bfv, acc[nf], 0, 0, 0);
            }
    }

    const int m0 = blockIdx.x * 32 + wave * 16 + lg * 4;   // rows m0..m0+3 (always 4-aligned)
    if (m0 < N_NODES) {
#pragma unroll
        for (int nf = 0; nf < 8; ++nf) {
            int c = nf * 16 + lr;
            ushort4 pk;
            pk.x = f2bf(acc[nf][0]); pk.y = f2bf(acc[nf][1]);
            pk.z = f2bf(acc[nf][2]); pk.w = f2bf(acc[nf][3]);
            *(ushort4*)(hT + (size_t)c * N_NODES + m0) = pk;
        }
    }
}

// ---------------- kernel 2: zp[split] = adj[:, ks] @ h[ks, :] ----------------
// A (adj f32) direct global->reg (cvt bf16 in reg); B (hT bf16) LDS double-buffered.
__global__ __launch_bounds__(128) void k_adj(const float* __restrict__ adj,
                                             const ushort* __restrict__ hT,
                                             float* __restrict__ zp) {
    __shared__ ushort Bs[2][BN][BK + 8];   // 2 x 128 x 72 bf16 = 36.9 KB

    const int tid = threadIdx.x, wave = tid >> 6, lane = tid & 63;
    const int lr = lane & 15, lg = lane >> 4;
    const int m0 = blockIdx.x * BM;
    const int split = blockIdx.y;
    const int step0 = split * STEPS_PER_SPLIT;
    const int nst = min(step0 + STEPS_PER_SPLIT, KSTEPS_TOTAL) - step0;

    const int arow = m0 + wave * 16 + lr;
    const bool aok = arow < N_NODES;
    const float* pA = adj + (size_t)arow * K_DIM;

    f32x4 acc[8];
#pragma unroll
    for (int nf = 0; nf < 8; ++nf) acc[nf] = (f32x4){0.f, 0.f, 0.f, 0.f};

    float4 A0[4], A1[4];
    uint4  B0[8], B1[8];

    auto loadA = [&](float4 (&A)[4], int st) {
        const int k0 = st * BK;
#pragma unroll
        for (int kh = 0; kh < 2; ++kh)
#pragma unroll
            for (int h = 0; h < 2; ++h) {
                int gk = k0 + kh * 32 + lg * 8 + h * 4;
                float4 val = make_float4(0.f, 0.f, 0.f, 0.f);
                if (aok && gk + 4 <= K_DIM) val = *(const float4*)(pA + gk);
                A[kh * 2 + h] = val;
            }
    };
    auto loadB = [&](uint4 (&B)[8], int st) {
        const int k0 = st * BK;
#pragma unroll
        for (int q = 0; q < 8; ++q) {
            int c = tid + q * 128;
            int row = c >> 3, gk = k0 + (c & 7) * 8;
            uint4 val = make_uint4(0u, 0u, 0u, 0u);
            if (gk + 8 <= K_DIM) val = *(const uint4*)(hT + (size_t)row * K_DIM + gk);
            B[q] = val;
        }
    };
    auto storeB = [&](int buf, uint4 (&B)[8]) {
#pragma unroll
        for (int q = 0; q < 8; ++q) {
            int c = tid + q * 128;
            *(uint4*)&Bs[buf][c >> 3][(c & 7) * 8] = B[q];
        }
    };
    auto compute = [&](float4 (&A)[4], int buf) {
#pragma unroll
        for (int kh = 0; kh < 2; ++kh) {
            bf16x8 abf;
            ushort* ap = (ushort*)&abf;
            const float* af = (const float*)&A[kh * 2];
#pragma unroll
            for (int e = 0; e < 8; ++e) ap[e] = f2bf(af[e]);
#pragma unroll
            for (int nf = 0; nf < 8; ++nf) {
                bf16x8 bfv = *(const bf16x8*)&Bs[buf][nf * 16 + lr][kh * 32 + lg * 8];
                acc[nf] = __builtin_amdgcn_mfma_f32_16x16x32_bf16(abf, bfv, acc[nf], 0, 0, 0);
            }
        }
    };

    // prologue
    loadA(A0, step0);
    loadB(B0, step0);
    storeB(0, B0);
    __syncthreads();

    int i = 0;
    while (true) {
        bool hn = (i + 1 < nst);
        if (hn) { loadA(A1, step0 + i + 1); loadB(B1, step0 + i + 1); }
        compute(A0, 0);
        if (hn) storeB(1, B1);
        __syncthreads();
        ++i; if (i >= nst) break;

        hn = (i + 1 < nst);
        if (hn) { loadA(A0, step0 + i + 1); loadB(B0, step0 + i + 1); }
        compute(A1, 1);
        if (hn) storeB(0, B0);
        __syncthreads();
        ++i; if (i >= nst) break;
    }

    // epilogue: write split-partial z
    float* out = zp + (size_t)split * N_NODES * OUT_DIM;
    const int orow = m0 + wave * 16 + lg * 4;
#pragma unroll
    for (int nf = 0; nf < 8; ++nf)
#pragma unroll
        for (int r = 0; r < 4; ++r) {
            int row = orow + r;
            if (row < N_NODES)
                out[(size_t)row * OUT_DIM + nf * 16 + lr] = acc[nf][r];
        }
}

// ---------------- kernel 3: reduce splits + per-node precompute ----------------
__global__ __launch_bounds__(256) void k_node(const float* __restrict__ zp,
                                              const float* __restrict__ v,
                                              const float* __restrict__ w3,
                                              float* __restrict__ a,
                                              float* __restrict__ b,
                                              ushort* __restrict__ zb,
                                              ushort* __restrict__ zwb) {
    const int wave = threadIdx.x >> 6, lane = threadIdx.x & 63;
    const int i = blockIdx.x * 4 + wave;
    if (i >= N_NODES) return;
    const int k0 = lane, k1 = lane + 64;

    float z0 = 0.f, z1 = 0.f;
#pragma unroll
    for (int s = 0; s < SPLITS; ++s) {
        const float* row = zp + ((size_t)s * N_NODES + i) * OUT_DIM;
        z0 += row[k0];
        z1 += row[k1];
    }
    zb[(size_t)i * OUT_DIM + k0]  = f2bf(z0);
    zb[(size_t)i * OUT_DIM + k1]  = f2bf(z1);
    zwb[(size_t)i * OUT_DIM + k0] = f2bf(z0 * w3[OUT_DIM + k0]);
    zwb[(size_t)i * OUT_DIM + k1] = f2bf(z1 * w3[OUT_DIM + k1]);

    float ra = fmaxf(z0, 0.f) * v[k0] + fmaxf(z1, 0.f) * v[k1];
    float rb = fmaxf(z0, 0.f) * v[OUT_DIM + k0] + fmaxf(z1, 0.f) * v[OUT_DIM + k1];
#pragma unroll
    for (int off = 32; off; off >>= 1) {
        ra += __shfl_down(ra, off);
        rb += __shfl_down(rb, off);
    }
    if (lane == 0) { a[i] = ra; b[i] = rb; }
}

// ---------------- kernel 4: per-edge logit + sigmoid (2 edges / wave) ----------------
__global__ __launch_bounds__(256) void k_edge(const int* __restrict__ e_true,
                                              const int* __restrict__ e_false,
                                              const float* __restrict__ a,
                                              const float* __restrict__ b,
                                              const ushort* __restrict__ zb,
                                              const ushort* __restrict__ zwb,
                                              float* __restrict__ out) {
    const int lane = threadIdx.x & 63;
    const int half = lane >> 5, l32 = lane & 31;
    const int gw   = (blockIdx.x * blockDim.x + threadIdx.x) >> 6;
    const int nw   = (gridDim.x * blockDim.x) >> 6;

    for (int e = gw * 2 + half; e < 2 * NE; e += nw * 2) {
        int2 ij = (e < NE) ? ((const int2*)e_true)[e] : ((const int2*)e_false)[e - NE];
        int i = ij.x, j = ij.y;

        uint2 zwi = *(const uint2*)(zwb + (size_t)i * OUT_DIM + l32 * 4);
        uint2 zjv = *(const uint2*)(zb  + (size_t)j * OUT_DIM + l32 * 4);
        float d = bf2f((ushort)(zwi.x & 0xffffu)) * bf2f((ushort)(zjv.x & 0xffffu))
                + bf2f((ushort)(zwi.x >> 16))     * bf2f((ushort)(zjv.x >> 16))
                + bf2f((ushort)(zwi.y & 0xffffu)) * bf2f((ushort)(zjv.y & 0xffffu))
                + bf2f((ushort)(zwi.y >> 16))     * bf2f((ushort)(zjv.y >> 16));
#pragma unroll
        for (int off = 16; off; off >>= 1) d += __shfl_xor(d, off, 32);
        if (l32 == 0) {
            float logit = a[i] + b[j] + d;
            out[e] = 1.0f / (1.0f + __expf(-logit));
        }
    }
}

// ---------------- launch ----------------
extern "C" void kernel_launch(void* const* d_in, const int* in_sizes, int n_in,
                              void* d_out, int out_size, void* d_ws, size_t ws_size,
                              hipStream_t stream) {
    const float* x      = (const float*)d_in[0];
    const float* adj    = (const float*)d_in[1];
    const float* w      = (const float*)d_in[2];
    const float* w2     = (const float*)d_in[3];
    const float* w3     = (const float*)d_in[4];
    const int* e_true   = (const int*)d_in[5];
    const int* e_false  = (const int*)d_in[6];
    float* out          = (float*)d_out;

    char* ws = (char*)d_ws;
    ushort* hT  = (ushort*)(ws);                        //  2,560,000
    float*  zp  = (float*)(ws + 2560000);               // 20,480,000
    float*  v   = (float*)(ws + 23040000);              //      1,024
    float*  a   = (float*)(ws + 23041024);              //     40,000
    float*  b   = (float*)(ws + 23081024);              //     40,000
    ushort* zb  = (ushort*)(ws + 23121024);             //  2,560,000
    ushort* zwb = (ushort*)(ws + 25681024);             //  2,560,000
    ushort* WT  = (ushort*)(ws + 28241024);             //    131,072  -> ~28.4 MB

    k_prep<<<1, 256, 0, stream>>>(w, w2, w3, WT, v);
    k_xw<<<313, 128, 0, stream>>>(x, WT, hT);
    k_adj<<<dim3(313, SPLITS), 128, 0, stream>>>(adj, hT, zp);
    k_node<<<2500, 256, 0, stream>>>(zp, v, w3, a, b, zb, zwb);
    k_edge<<<2048, 256, 0, stream>>>(e_true, e_false, a, b, zb, zwb, out);
}

// Round 3
// 206.002 us; speedup vs baseline: 1.6976x; 1.6976x over previous
//
#include <hip/hip_runtime.h>

// ---------------- problem constants ----------------
#define N_NODES 10000
#define IN_DIM  512
#define OUT_DIM 128
#define NE      262144
#define K_DIM   10000
#define HT_S    10048          // padded hT stride (zeros in [10000,10048))

// ---------------- GEMM2 (adj @ h) tiling ----------------
#define BM 64
#define BN 128
#define BK 64
#define SPLITS 8
#define KSTEPS_TOTAL 157       // ceil(10000/64)
#define STEPS_PER_SPLIT 20     // 7*20 + 17 = 157

typedef __attribute__((ext_vector_type(8))) __bf16 bf16x8;
typedef __attribute__((ext_vector_type(4))) float  f32x4;

__device__ inline ushort f2bf(float f) {
    uint u = __float_as_uint(f);
    return (ushort)((u + 0x7fffu + ((u >> 16) & 1u)) >> 16);
}
__device__ inline float bf2f(ushort s) {
    return __uint_as_float(((uint)s) << 16);
}

// async global -> LDS, 16 bytes per lane (global_load_lds_dwordx4)
__device__ __forceinline__ void gl2lds16(const void* g, void* l) {
    __builtin_amdgcn_global_load_lds(
        (const __attribute__((address_space(1))) void*)g,
        (__attribute__((address_space(3))) void*)l, 16, 0, 0);
}

// ---------------- kernel 0: WT = W^T bf16, v = W2 @ w3[:128], hT pad zero ----
__global__ __launch_bounds__(256) void k_prep(const float* __restrict__ w,
                                              const float* __restrict__ w2,
                                              const float* __restrict__ w3,
                                              ushort* __restrict__ WT,
                                              float* __restrict__ v,
                                              ushort* __restrict__ hT) {
    const int t = threadIdx.x;
    for (int idx = blockIdx.x * 256 + t; idx < IN_DIM * OUT_DIM; idx += gridDim.x * 256) {
        int k = idx >> 7, n = idx & 127;
        WT[n * IN_DIM + k] = f2bf(w[idx]);
    }
    if (blockIdx.x == 0) {
        float s = 0.f;
        for (int j = 0; j < OUT_DIM; ++j) s += w2[t * OUT_DIM + j] * w3[j];
        v[t] = s;
    }
    if (blockIdx.x == 1) {
        for (int idx = t; idx < 128 * (HT_S - N_NODES); idx += 256) {
            int c = idx / (HT_S - N_NODES), r = idx % (HT_S - N_NODES);
            hT[(size_t)c * HT_S + N_NODES + r] = 0;
        }
    }
}

// ---------------- kernel 1: hT[c][r] = (x @ W)[r][c] bf16, MFMA ----------------
__global__ __launch_bounds__(128) void k_xw(const float* __restrict__ x,
                                            const ushort* __restrict__ WT,
                                            ushort* __restrict__ hT) {
    const int tid = threadIdx.x, wave = tid >> 6, lane = tid & 63;
    const int lr = lane & 15, lg = lane >> 4;
    const int arow = blockIdx.x * 32 + wave * 16 + lr;
    const bool aok = arow < N_NODES;
    const float* pA = x + (size_t)arow * IN_DIM;

    f32x4 acc[8];
#pragma unroll
    for (int nf = 0; nf < 8; ++nf) acc[nf] = (f32x4){0.f, 0.f, 0.f, 0.f};

#pragma unroll 2
    for (int st = 0; st < 8; ++st) {
        const int k0 = st * 64;
        bf16x8 abf[2];
#pragma unroll
        for (int kh = 0; kh < 2; ++kh) {
            float4 a0 = make_float4(0.f, 0.f, 0.f, 0.f), a1 = a0;
            if (aok) {
                a0 = *(const float4*)(pA + k0 + kh * 32 + lg * 8);
                a1 = *(const float4*)(pA + k0 + kh * 32 + lg * 8 + 4);
            }
            ushort* ap = (ushort*)&abf[kh];
            ap[0] = f2bf(a0.x); ap[1] = f2bf(a0.y); ap[2] = f2bf(a0.z); ap[3] = f2bf(a0.w);
            ap[4] = f2bf(a1.x); ap[5] = f2bf(a1.y); ap[6] = f2bf(a1.z); ap[7] = f2bf(a1.w);
        }
#pragma unroll
        for (int kh = 0; kh < 2; ++kh)
#pragma unroll
            for (int nf = 0; nf < 8; ++nf) {
                bf16x8 bfv = *(const bf16x8*)(WT + (size_t)(nf * 16 + lr) * IN_DIM + k0 + kh * 32 + lg * 8);
                acc[nf] = __builtin_amdgcn_mfma_f32_16x16x32_bf16(abf[kh], bfv, acc[nf], 0, 0, 0);
            }
    }

    const int m0 = blockIdx.x * 32 + wave * 16 + lg * 4;
    if (m0 < N_NODES) {
#pragma unroll
        for (int nf = 0; nf < 8; ++nf) {
            int c = nf * 16 + lr;
            ushort4 pk;
            pk.x = f2bf(acc[nf][0]); pk.y = f2bf(acc[nf][1]);
            pk.z = f2bf(acc[nf][2]); pk.w = f2bf(acc[nf][3]);
            *(ushort4*)(hT + (size_t)c * HT_S + m0) = pk;
        }
    }
}

// ---------------- kernel 2: zp[split] = adj @ h, m97-style global_load_lds ----
// A: f32 [64 rows][256B], swizzled: phys_off = log_off ^ ((row&7)<<4)
// B: bf16 [128 rows][128B], swizzled likewise. Both staged async, 1 buffer,
// 2 barriers per K-step (m97). A converted f32->bf16 at fragment read.
__global__ __launch_bounds__(256) void k_adj(const float* __restrict__ adj,
                                             const ushort* __restrict__ hT,
                                             float* __restrict__ zp) {
    __shared__ float  As[BM * BK];        // 16 KB
    __shared__ ushort Bs[BN * BK];        // 16 KB

    const int tid = threadIdx.x, wave = tid >> 6, lane = tid & 63;
    const int lr = lane & 15, lg = lane >> 4;
    const int m0 = blockIdx.x * BM;
    const int split = blockIdx.y;
    const int step0 = split * STEPS_PER_SPLIT;
    const int step1 = min(step0 + STEPS_PER_SPLIT, KSTEPS_TOTAL);

    // --- per-thread staging descriptors (loop-invariant) ---
    // A: 1024 chunks of 16B; chunk c: row=c>>4, ch=c&15, src chunk = ch^(row&7)
    long  abase[4];
    char* aldst[4];
#pragma unroll
    for (int q = 0; q < 4; ++q) {
        int c = tid + q * 256;
        int row = c >> 4, ch = c & 15;
        int grow = m0 + row; if (grow > N_NODES - 1) grow = N_NODES - 1;
        abase[q] = (long)grow * K_DIM + (long)((ch ^ (row & 7)) * 4);
        aldst[q] = (char*)As + c * 16;
    }
    // B: 1024 chunks of 16B; chunk c: row=c>>3, ch=c&7, src chunk = ch^(row&7)
    long  bbase[4];
    char* bldst[4];
#pragma unroll
    for (int q = 0; q < 4; ++q) {
        int c = tid + q * 256;
        int row = c >> 3, ch = c & 7;
        bbase[q] = (long)row * HT_S + (long)((ch ^ (row & 7)) * 8);
        bldst[q] = (char*)Bs + c * 16;
    }
    const long ALIMIT = (long)K_DIM * N_NODES - 4;

    f32x4 acc[8];
#pragma unroll
    for (int nf = 0; nf < 8; ++nf) acc[nf] = (f32x4){0.f, 0.f, 0.f, 0.f};

    const int  arow  = wave * 16 + lr;
    const int  asw   = (arow & 7) << 4;
    const int  abyte = arow * 256;
    const char* Ab = (const char*)As;
    const char* Bb = (const char*)Bs;

    for (int st = step0; st < step1; ++st) {
        const int k0 = st * BK;

        // stage A (HBM) then B (L2) — async DMA
#pragma unroll
        for (int q = 0; q < 4; ++q) {
            long off = abase[q] + k0;
            if (off > ALIMIT) off = ALIMIT;
            gl2lds16(adj + off, aldst[q]);
        }
#pragma unroll
        for (int q = 0; q < 4; ++q)
            gl2lds16(hT + (bbase[q] + k0), bldst[q]);

        __syncthreads();   // vmcnt(0) drain + barrier: tiles ready

#pragma unroll
        for (int kh = 0; kh < 2; ++kh) {
            int o0 = kh * 128 + lg * 32;
            float4 fa0 = *(const float4*)(Ab + abyte + ((o0)      ^ asw));
            float4 fa1 = *(const float4*)(Ab + abyte + ((o0 + 16) ^ asw));
            bf16x8 abf;
            ushort* ap = (ushort*)&abf;
            ap[0] = f2bf(fa0.x); ap[1] = f2bf(fa0.y); ap[2] = f2bf(fa0.z); ap[3] = f2bf(fa0.w);
            ap[4] = f2bf(fa1.x); ap[5] = f2bf(fa1.y); ap[6] = f2bf(fa1.z); ap[7] = f2bf(fa1.w);
#pragma unroll
            for (int nf = 0; nf < 8; ++nf) {
                int brow = nf * 16 + lr;
                bf16x8 bv = *(const bf16x8*)(Bb + brow * 128 + ((kh * 64 + lg * 16) ^ ((brow & 7) << 4)));
                acc[nf] = __builtin_amdgcn_mfma_f32_16x16x32_bf16(abf, bv, acc[nf], 0, 0, 0);
            }
        }

        __syncthreads();   // protect LDS before next-step overwrite
    }

    // epilogue: write split-partial z
    float* out = zp + (size_t)split * N_NODES * OUT_DIM;
    const int orow = m0 + wave * 16 + lg * 4;
#pragma unroll
    for (int nf = 0; nf < 8; ++nf)
#pragma unroll
        for (int r = 0; r < 4; ++r) {
            int row = orow + r;
            if (row < N_NODES)
                out[(size_t)row * OUT_DIM + nf * 16 + lr] = acc[nf][r];
        }
}

// ---------------- kernel 3: reduce splits + per-node precompute ----------------
__global__ __launch_bounds__(256) void k_node(const float* __restrict__ zp,
                                              const float* __restrict__ v,
                                              const float* __restrict__ w3,
                                              float* __restrict__ a,
                                              float* __restrict__ b,
                                              ushort* __restrict__ zb,
                                              ushort* __restrict__ zwb) {
    const int wave = threadIdx.x >> 6, lane = threadIdx.x & 63;
    const int i = blockIdx.x * 4 + wave;
    if (i >= N_NODES) return;
    const int k0 = lane, k1 = lane + 64;

    float z0 = 0.f, z1 = 0.f;
#pragma unroll
    for (int s = 0; s < SPLITS; ++s) {
        const float* row = zp + ((size_t)s * N_NODES + i) * OUT_DIM;
        z0 += row[k0];
        z1 += row[k1];
    }
    zb[(size_t)i * OUT_DIM + k0]  = f2bf(z0);
    zb[(size_t)i * OUT_DIM + k1]  = f2bf(z1);
    zwb[(size_t)i * OUT_DIM + k0] = f2bf(z0 * w3[OUT_DIM + k0]);
    zwb[(size_t)i * OUT_DIM + k1] = f2bf(z1 * w3[OUT_DIM + k1]);

    float ra = fmaxf(z0, 0.f) * v[k0] + fmaxf(z1, 0.f) * v[k1];
    float rb = fmaxf(z0, 0.f) * v[OUT_DIM + k0] + fmaxf(z1, 0.f) * v[OUT_DIM + k1];
#pragma unroll
    for (int off = 32; off; off >>= 1) {
        ra += __shfl_down(ra, off);
        rb += __shfl_down(rb, off);
    }
    if (lane == 0) { a[i] = ra; b[i] = rb; }
}

// ---------------- kernel 4: per-edge logit + sigmoid (2 edges / wave) ----------
__global__ __launch_bounds__(256) void k_edge(const int* __restrict__ e_true,
                                              const int* __restrict__ e_false,
                                              const float* __restrict__ a,
                                              const float* __restrict__ b,
                                              const ushort* __restrict__ zb,
                                              const ushort* __restrict__ zwb,
                                              float* __restrict__ out) {
    const int lane = threadIdx.x & 63;
    const int half = lane >> 5, l32 = lane & 31;
    const int gw   = (blockIdx.x * blockDim.x + threadIdx.x) >> 6;
    const int nw   = (gridDim.x * blockDim.x) >> 6;

    for (int e = gw * 2 + half; e < 2 * NE; e += nw * 2) {
        int2 ij = (e < NE) ? ((const int2*)e_true)[e] : ((const int2*)e_false)[e - NE];
        int i = ij.x, j = ij.y;

        uint2 zwi = *(const uint2*)(zwb + (size_t)i * OUT_DIM + l32 * 4);
        uint2 zjv = *(const uint2*)(zb  + (size_t)j * OUT_DIM + l32 * 4);
        float d = bf2f((ushort)(zwi.x & 0xffffu)) * bf2f((ushort)(zjv.x & 0xffffu))
                + bf2f((ushort)(zwi.x >> 16))     * bf2f((ushort)(zjv.x >> 16))
                + bf2f((ushort)(zwi.y & 0xffffu)) * bf2f((ushort)(zjv.y & 0xffffu))
                + bf2f((ushort)(zwi.y >> 16))     * bf2f((ushort)(zjv.y >> 16));
#pragma unroll
        for (int off = 16; off; off >>= 1) d += __shfl_xor(d, off, 32);
        if (l32 == 0) {
            float logit = a[i] + b[j] + d;
            out[e] = 1.0f / (1.0f + __expf(-logit));
        }
    }
}

// ---------------- launch ----------------
extern "C" void kernel_launch(void* const* d_in, const int* in_sizes, int n_in,
                              void* d_out, int out_size, void* d_ws, size_t ws_size,
                              hipStream_t stream) {
    const float* x      = (const float*)d_in[0];
    const float* adj    = (const float*)d_in[1];
    const float* w      = (const float*)d_in[2];
    const float* w2     = (const float*)d_in[3];
    const float* w3     = (const float*)d_in[4];
    const int* e_true   = (const int*)d_in[5];
    const int* e_false  = (const int*)d_in[6];
    float* out          = (float*)d_out;

    char* ws = (char*)d_ws;
    // workspace layout (bytes)
    ushort* hT  = (ushort*)(ws);                        //  2,572,288 (128 x 10048 bf16)
    float*  zp  = (float*)(ws + 2572288);               // 40,960,000 (8 x 10000 x 128 f32)
    float*  v   = (float*)(ws + 43532288);              //      1,024
    float*  a   = (float*)(ws + 43533312);              //     40,000
    float*  b   = (float*)(ws + 43573312);              //     40,000
    ushort* zb  = (ushort*)(ws + 43613312);             //  2,560,000
    ushort* zwb = (ushort*)(ws + 46173312);             //  2,560,000
    ushort* WT  = (ushort*)(ws + 48733312);             //    131,072  -> ~48.9 MB

    k_prep<<<64, 256, 0, stream>>>(w, w2, w3, WT, v, hT);
    k_xw<<<313, 128, 0, stream>>>(x, WT, hT);
    k_adj<<<dim3(157, SPLITS), 256, 0, stream>>>(adj, hT, zp);
    k_node<<<2500, 256, 0, stream>>>(zp, v, w3, a, b, zb, zwb);
    k_edge<<<2048, 256, 0, stream>>>(e_true, e_false, a, b, zb, zwb, out);
}